// Round 3
// baseline (104.539 us; speedup 1.0000x reference)
//
#include <hip/hip_runtime.h>
#include <math.h>

namespace {
constexpr int D = 128;
constexpr int K = 8;
constexpr float BOUND = 3.0f;
constexpr float EPS = 1e-6f;
constexpr float MIN_BIN_W = 1e-3f;
constexpr float MIN_BIN_H = 1e-3f;
constexpr float MIN_DERIV = 1e-3f;
constexpr int REC = 8;           // floats per (dim,bin) record, two float4s
constexpr int S = K * REC + 4;   // 68 floats per dim row: 16B aligned, staggers banks
constexpr int WPB = 4;           // waves per 256-thread block
}

// record: ra = {icw, inv_w, d0, delta}, rb = {ich, ih, d1, E=d0+d1-2*delta}
__device__ __forceinline__ float spline_elem(float xv, const float* __restrict__ row,
                                             const float* kn, float* __restrict__ outp) {
    const bool inside = (xv >= -BOUND) & (xv <= BOUND);
    const float xc = fminf(fmaxf(xv, -BOUND), BOUND);
    int idx = 0;
    #pragma unroll
    for (int j = 0; j < 7; ++j) idx += (xc >= kn[j]) ? 1 : 0;
    const float4 ra = *(const float4*)(row + idx * REC);
    const float4 rb = *(const float4*)(row + idx * REC + 4);
    const float theta = (xc - ra.x) * ra.y;
    const float omt   = 1.f - theta;
    const float t1m   = theta * omt;
    const float th2   = theta * theta;
    const float num   = rb.y * (ra.w * th2 + ra.z * t1m);
    const float den   = ra.w + rb.w * t1m;
    const float rd    = __builtin_amdgcn_rcpf(den);
    const float outv  = fmaf(num, rd, rb.x);
    const float dnum  = ra.w * ra.w * (rb.z * th2 + 2.f * ra.w * t1m + ra.z * omt * omt);
    const float lad   = __logf(dnum * rd * rd);   // log(dnum) - 2*log(den)
    *outp = inside ? outv : xv;
    return inside ? lad : 0.f;
}

__global__ __launch_bounds__(256, 4) void spline_fwd(
    const float* __restrict__ x,
    const float* __restrict__ uw,
    const float* __restrict__ uh,
    const float* __restrict__ ud,
    float* __restrict__ out_u,
    float* __restrict__ out_ld,
    int nrows)
{
    __shared__ __align__(16) float s_tab[D * S];

    const int tid = threadIdx.x;
    if (tid < D) {
        const int d = tid;
        float wv[K], hv[K], cw[K + 1], ch[K + 1], der[K + 1];

        // softmax over unnormalized widths
        {
            const float* p = uw + d * K;
            float m = p[0];
            #pragma unroll
            for (int j = 1; j < K; ++j) m = fmaxf(m, p[j]);
            float s = 0.f;
            #pragma unroll
            for (int j = 0; j < K; ++j) { wv[j] = __expf(p[j] - m); s += wv[j]; }
            const float inv = 1.f / s;
            #pragma unroll
            for (int j = 0; j < K; ++j)
                wv[j] = MIN_BIN_W + (1.f - MIN_BIN_W * K) * (wv[j] * inv);
        }
        // softmax over unnormalized heights
        {
            const float* p = uh + d * K;
            float m = p[0];
            #pragma unroll
            for (int j = 1; j < K; ++j) m = fmaxf(m, p[j]);
            float s = 0.f;
            #pragma unroll
            for (int j = 0; j < K; ++j) { hv[j] = __expf(p[j] - m); s += hv[j]; }
            const float inv = 1.f / s;
            #pragma unroll
            for (int j = 0; j < K; ++j)
                hv[j] = MIN_BIN_H + (1.f - MIN_BIN_H * K) * (hv[j] * inv);
        }
        // knots (cumsum, scale to [-BOUND,BOUND], pin endpoints)
        cw[0] = -BOUND; ch[0] = -BOUND;
        float cs_w = 0.f, cs_h = 0.f;
        #pragma unroll
        for (int j = 0; j < K; ++j) {
            cs_w += wv[j]; cw[j + 1] = 2.f * BOUND * cs_w - BOUND;
            cs_h += hv[j]; ch[j + 1] = 2.f * BOUND * cs_h - BOUND;
        }
        cw[K] = BOUND; ch[K] = BOUND;

        // derivatives: softplus + MIN_DERIV, boundaries = 1 - MIN_DERIV
        der[0] = 1.f - MIN_DERIV;
        der[K] = 1.f - MIN_DERIV;
        {
            const float* p = ud + d * (K - 1);
            #pragma unroll
            for (int j = 1; j < K; ++j) {
                const float v = p[j - 1];
                const float sp = log1pf(__expf(-fabsf(v))) + fmaxf(v, 0.f);
                der[j] = MIN_DERIV + sp;
            }
        }

        float* row = s_tab + d * S;
        #pragma unroll
        for (int j = 0; j < K; ++j) {
            const float w  = cw[j + 1] - cw[j];
            const float h  = ch[j + 1] - ch[j];
            const float dl = h / w;
            row[j * REC + 0] = cw[j];
            row[j * REC + 1] = 1.f / w;
            row[j * REC + 2] = der[j];
            row[j * REC + 3] = dl;
            row[j * REC + 4] = ch[j];
            row[j * REC + 5] = h;
            row[j * REC + 6] = der[j + 1];
            row[j * REC + 7] = der[j] + der[j + 1] - 2.f * dl;
        }
    }
    __syncthreads();

    const int wave = tid >> 6;
    const int lane = tid & 63;
    const int l32  = lane & 31;
    const int half = lane >> 5;          // 0 -> even row of pair, 1 -> odd row
    const int dbase = l32 << 2;          // this lane's 4 dims: dbase..dbase+3

    const float* rowp0 = s_tab + (dbase + 0) * S;
    const float* rowp1 = s_tab + (dbase + 1) * S;
    const float* rowp2 = s_tab + (dbase + 2) * S;
    const float* rowp3 = s_tab + (dbase + 3) * S;

    // interior knots (+EPS folded) in registers: icw of bin j IS knot j
    float kn[28];
    #pragma unroll
    for (int j = 0; j < 7; ++j) {
        kn[j]      = rowp0[(j + 1) * REC] + EPS;
        kn[7 + j]  = rowp1[(j + 1) * REC] + EPS;
        kn[14 + j] = rowp2[(j + 1) * REC] + EPS;
        kn[21 + j] = rowp3[(j + 1) * REC] + EPS;
    }

    const int npairs = nrows >> 1;                 // one float4-wave-load covers 2 rows
    const int gw = blockIdx.x * WPB + wave;
    const int nw = gridDim.x * WPB;
    const int lo4 = lane << 2;

    for (int p = gw * 2; p < npairs; p += nw * 2) {
        const int r0 = p * 2;                       // rows r0, r0+1
        const float4 xa = *(const float4*)(x + (size_t)r0 * D + lo4);
        const bool two = (p + 1) < npairs;
        const int r2 = two ? (p + 1) * 2 : r0;      // rows r2, r2+1
        const float4 xb = *(const float4*)(x + (size_t)r2 * D + lo4);

        float4 ua, ub;
        float la, lb;
        la  = spline_elem(xa.x, rowp0, kn +  0, &ua.x);
        la += spline_elem(xa.y, rowp1, kn +  7, &ua.y);
        la += spline_elem(xa.z, rowp2, kn + 14, &ua.z);
        la += spline_elem(xa.w, rowp3, kn + 21, &ua.w);
        lb  = spline_elem(xb.x, rowp0, kn +  0, &ub.x);
        lb += spline_elem(xb.y, rowp1, kn +  7, &ub.y);
        lb += spline_elem(xb.z, rowp2, kn + 14, &ub.z);
        lb += spline_elem(xb.w, rowp3, kn + 21, &ub.w);

        *(float4*)(out_u + (size_t)r0 * D + lo4) = ua;
        if (two) *(float4*)(out_u + (size_t)r2 * D + lo4) = ub;

        // butterfly within each 32-lane half: both rows reduced simultaneously
        la += __shfl_xor(la, 1);  lb += __shfl_xor(lb, 1);
        la += __shfl_xor(la, 2);  lb += __shfl_xor(lb, 2);
        la += __shfl_xor(la, 4);  lb += __shfl_xor(lb, 4);
        la += __shfl_xor(la, 8);  lb += __shfl_xor(lb, 8);
        la += __shfl_xor(la, 16); lb += __shfl_xor(lb, 16);

        if (l32 == 0) {
            out_ld[r0 + half] = la;
            if (two) out_ld[r2 + half] = lb;
        }
    }
}

extern "C" void kernel_launch(void* const* d_in, const int* in_sizes, int n_in,
                              void* d_out, int out_size, void* d_ws, size_t ws_size,
                              hipStream_t stream) {
    const float* x  = (const float*)d_in[0];
    const float* uw = (const float*)d_in[1];
    const float* uh = (const float*)d_in[2];
    const float* ud = (const float*)d_in[3];
    const int nrows = in_sizes[0] / D;
    float* out_u  = (float*)d_out;
    float* out_ld = (float*)d_out + (size_t)nrows * D;
    // grid 1024 = exactly 4 blocks/CU at 34.8 KB LDS -> 16 waves/CU
    spline_fwd<<<1024, 256, 0, stream>>>(x, uw, uh, ud, out_u, out_ld, nrows);
}

// Round 4
// 102.745 us; speedup vs baseline: 1.0175x; 1.0175x over previous
//
#include <hip/hip_runtime.h>
#include <math.h>

namespace {
constexpr int D = 128;
constexpr int K = 8;
constexpr float BOUND = 3.0f;
constexpr float EPS = 1e-6f;
constexpr float MIN_BIN_W = 1e-3f;
constexpr float MIN_BIN_H = 1e-3f;
constexpr float MIN_DERIV = 1e-3f;
constexpr float LN2 = 0.6931471805599453f;
constexpr int REC = 8;           // floats per (dim,bin) record, two float4s
constexpr int S = K * REC + 4;   // 68 floats per slot row: 16B aligned, 8-way bank-start spread
constexpr int WPB = 4;           // waves per 256-thread block
constexpr int PPW = 4;           // row-pairs per wave (static schedule)
}

// record: ra = {icw, inv_w, d0, delta}, rb = {ich, ih, d1, E=d0+d1-2*delta}
// returns log2-domain lad contribution
__device__ __forceinline__ float spline_elem(float xv, const float* __restrict__ row,
                                             const float* kn, float* __restrict__ outp) {
    const bool inside = (xv >= -BOUND) & (xv <= BOUND);
    const float xc = fminf(fmaxf(xv, -BOUND), BOUND);
    int idx = 0;
    #pragma unroll
    for (int j = 0; j < 7; ++j) idx += (xc >= kn[j]) ? 1 : 0;
    const float4 ra = *(const float4*)(row + idx * REC);
    const float4 rb = *(const float4*)(row + idx * REC + 4);
    const float theta = (xc - ra.x) * ra.y;
    const float omt   = 1.f - theta;
    const float t1m   = theta * omt;
    const float th2   = theta * theta;
    const float num   = rb.y * (ra.w * th2 + ra.z * t1m);
    const float den   = ra.w + rb.w * t1m;
    const float rd    = __builtin_amdgcn_rcpf(den);
    const float outv  = fmaf(num, rd, rb.x);
    const float dnum  = ra.w * ra.w * (rb.z * th2 + 2.f * ra.w * t1m + ra.z * omt * omt);
    const float lad   = __log2f(dnum * rd * rd);   // (log(dnum)-2log(den))/ln2
    *outp = inside ? outv : xv;
    return inside ? lad : 0.f;
}

__global__ __launch_bounds__(256) void spline_fwd(
    const float* __restrict__ x,
    const float* __restrict__ uw,
    const float* __restrict__ uh,
    const float* __restrict__ ud,
    float* __restrict__ out_u,
    float* __restrict__ out_ld,
    int nrows)
{
    __shared__ __align__(16) float s_tab[D * S];

    const int tid = threadIdx.x;
    if (tid < D) {
        const int d = tid;
        float wv[K], hv[K], cw[K + 1], ch[K + 1], der[K + 1];

        // softmax over unnormalized widths
        {
            const float* p = uw + d * K;
            float m = p[0];
            #pragma unroll
            for (int j = 1; j < K; ++j) m = fmaxf(m, p[j]);
            float s = 0.f;
            #pragma unroll
            for (int j = 0; j < K; ++j) { wv[j] = __expf(p[j] - m); s += wv[j]; }
            const float inv = 1.f / s;
            #pragma unroll
            for (int j = 0; j < K; ++j)
                wv[j] = MIN_BIN_W + (1.f - MIN_BIN_W * K) * (wv[j] * inv);
        }
        // softmax over unnormalized heights
        {
            const float* p = uh + d * K;
            float m = p[0];
            #pragma unroll
            for (int j = 1; j < K; ++j) m = fmaxf(m, p[j]);
            float s = 0.f;
            #pragma unroll
            for (int j = 0; j < K; ++j) { hv[j] = __expf(p[j] - m); s += hv[j]; }
            const float inv = 1.f / s;
            #pragma unroll
            for (int j = 0; j < K; ++j)
                hv[j] = MIN_BIN_H + (1.f - MIN_BIN_H * K) * (hv[j] * inv);
        }
        // knots (cumsum, scale to [-BOUND,BOUND], pin endpoints)
        cw[0] = -BOUND; ch[0] = -BOUND;
        float cs_w = 0.f, cs_h = 0.f;
        #pragma unroll
        for (int j = 0; j < K; ++j) {
            cs_w += wv[j]; cw[j + 1] = 2.f * BOUND * cs_w - BOUND;
            cs_h += hv[j]; ch[j + 1] = 2.f * BOUND * cs_h - BOUND;
        }
        cw[K] = BOUND; ch[K] = BOUND;

        // derivatives: softplus + MIN_DERIV, boundaries = 1 - MIN_DERIV
        der[0] = 1.f - MIN_DERIV;
        der[K] = 1.f - MIN_DERIV;
        {
            const float* p = ud + d * (K - 1);
            #pragma unroll
            for (int j = 1; j < K; ++j) {
                const float v = p[j - 1];
                const float sp = log1pf(__expf(-fabsf(v))) + fmaxf(v, 0.f);
                der[j] = MIN_DERIV + sp;
            }
        }

        // slot permutation: dim d -> slot (d&3)*32 + (d>>2), so a lane's 4 dims
        // sit at lane-stride-1 slots => 68-dword stride => 8-way bank-start spread
        float* row = s_tab + ((d & 3) * 32 + (d >> 2)) * S;
        #pragma unroll
        for (int j = 0; j < K; ++j) {
            const float w  = cw[j + 1] - cw[j];
            const float h  = ch[j + 1] - ch[j];
            const float dl = h / w;
            row[j * REC + 0] = cw[j];
            row[j * REC + 1] = 1.f / w;
            row[j * REC + 2] = der[j];
            row[j * REC + 3] = dl;
            row[j * REC + 4] = ch[j];
            row[j * REC + 5] = h;
            row[j * REC + 6] = der[j + 1];
            row[j * REC + 7] = der[j] + der[j + 1] - 2.f * dl;
        }
    }
    __syncthreads();

    const int wave = tid >> 6;
    const int lane = tid & 63;
    const int l32  = lane & 31;
    const int half = lane >> 5;          // row 2p (lanes 0-31) or 2p+1 (lanes 32-63)

    // this lane's 4 dims are 4*l32 + c, living at slots c*32 + l32
    const float* rowp0 = s_tab + (0 * 32 + l32) * S;
    const float* rowp1 = s_tab + (1 * 32 + l32) * S;
    const float* rowp2 = s_tab + (2 * 32 + l32) * S;
    const float* rowp3 = s_tab + (3 * 32 + l32) * S;

    // interior knots (+EPS folded) in registers: icw of bin j+1 IS interior knot j
    float kn[28];
    #pragma unroll
    for (int j = 0; j < 7; ++j) {
        kn[j]      = rowp0[(j + 1) * REC] + EPS;
        kn[7 + j]  = rowp1[(j + 1) * REC] + EPS;
        kn[14 + j] = rowp2[(j + 1) * REC] + EPS;
        kn[21 + j] = rowp3[(j + 1) * REC] + EPS;
    }

    const int npairs = nrows >> 1;               // one dwordx4 wave-load = 2 rows
    const int p0 = (blockIdx.x * WPB + wave) * PPW;
    const int lo4 = lane << 2;

    // issue all 4 pair-loads before any compute: 4 KB outstanding per wave
    float4 xv[PPW];
    #pragma unroll
    for (int c = 0; c < PPW; ++c) {
        const int p = p0 + c;
        const int pc = (p < npairs) ? p : (npairs - 1);
        xv[c] = *(const float4*)(x + (size_t)(pc * 2) * D + lo4);
    }

    #pragma unroll
    for (int c = 0; c < PPW; ++c) {
        const int p = p0 + c;
        if (p < npairs) {
            float4 u;
            float la;
            la  = spline_elem(xv[c].x, rowp0, kn +  0, &u.x);
            la += spline_elem(xv[c].y, rowp1, kn +  7, &u.y);
            la += spline_elem(xv[c].z, rowp2, kn + 14, &u.z);
            la += spline_elem(xv[c].w, rowp3, kn + 21, &u.w);

            *(float4*)(out_u + (size_t)(p * 2) * D + lo4) = u;

            // butterfly within each 32-lane half: both rows of the pair at once
            la += __shfl_xor(la, 1);
            la += __shfl_xor(la, 2);
            la += __shfl_xor(la, 4);
            la += __shfl_xor(la, 8);
            la += __shfl_xor(la, 16);
            if (l32 == 0) out_ld[p * 2 + half] = la * LN2;
        }
    }
}

extern "C" void kernel_launch(void* const* d_in, const int* in_sizes, int n_in,
                              void* d_out, int out_size, void* d_ws, size_t ws_size,
                              hipStream_t stream) {
    const float* x  = (const float*)d_in[0];
    const float* uw = (const float*)d_in[1];
    const float* uh = (const float*)d_in[2];
    const float* ud = (const float*)d_in[3];
    const int nrows = in_sizes[0] / D;
    float* out_u  = (float*)d_out;
    float* out_ld = (float*)d_out + (size_t)nrows * D;
    // static schedule: 8192 waves x 4 pairs = 32768 pairs = 65536 rows exactly
    const int npairs = nrows / 2;
    const int nwaves = (npairs + PPW - 1) / PPW;
    const int nblocks = (nwaves + WPB - 1) / WPB;
    spline_fwd<<<nblocks, 256, 0, stream>>>(x, uw, uh, ud, out_u, out_ld, nrows);
}